// Round 1
// baseline (183.086 us; speedup 1.0000x reference)
//
#include <hip/hip_runtime.h>
#include <math.h>

// TaskAdaptiveRouter: logits = x @ Wr[:, :2048]^T + task_logits; softmax; top2; aux.
// B=4, L=4096 -> 16384 tokens; D=2048; DT=16; E=64; TOP_K=2; TEMPERATURE=1.
//
// d_out (f32 flat): [0,32768) topw ; [32768,65536) topi (as floats) ;
//                   [65536,1114112) probs ; [1114112] aux_loss.
// d_ws  (f32): [0,256) task_logits tl[4][64] ; [256,320) Pacc[64] ; [320,384) Facc[64]

#define NTOK   16384
#define DIM    2048
#define WROW   2064      // W_router row stride = D + DT
#define NEXP   64
#define BK     64
#define NTILE  32        // 2048 / 64
#define SX     68        // padded LDS stride (floats): 16B-aligned float4s, 2-way banks

// ---------------- kernel 1: task projection + task logits + zero accumulators ----
__global__ void k1_task(const float* __restrict__ z, const float* __restrict__ Wp,
                        const float* __restrict__ bp, const float* __restrict__ Wr,
                        const float* __restrict__ eb, float* __restrict__ ws) {
    __shared__ float tp[4][16];
    const int t = threadIdx.x;
    if (t < 64) {
        const int b = t >> 4, r = t & 15;
        float s = bp[r];
        #pragma unroll
        for (int i = 0; i < 16; ++i) s += z[b * 16 + i] * Wp[r * 16 + i];
        // exact GELU: 0.5*x*(1+erf(x/sqrt(2)))
        tp[b][r] = 0.5f * s * (1.0f + erff(s * 0.70710678118654752440f));
    }
    if (t < 128) ws[256 + t] = 0.0f;   // zero Pacc[64] + Facc[64]
    __syncthreads();
    {
        const int b = t >> 6, e = t & 63;
        const float* wr = Wr + (size_t)e * WROW + DIM;
        float s = eb[e];
        #pragma unroll
        for (int i = 0; i < 16; ++i) s += tp[b][i] * wr[i];
        ws[b * 64 + e] = s;
    }
}

// ---------------- epilogue helper (templated on wave id -> all-static indexing) ---
template <int W>
__device__ __forceinline__ void epi_part(const float (&v)[64], float rZ, int i1, int i2,
                                         float* __restrict__ pb, float* __restrict__ Pacc,
                                         float* __restrict__ Facc, int lane) {
    // probs store: this wave writes column chunks [4W, 4W+4) for its lane's token row
    #pragma unroll
    for (int c = 0; c < 4; ++c) {
        const int cc = W * 4 + c;
        float4 o;
        o.x = v[4 * cc + 0] * rZ; o.y = v[4 * cc + 1] * rZ;
        o.z = v[4 * cc + 2] * rZ; o.w = v[4 * cc + 3] * rZ;
        *(float4*)(pb + cc * 4) = o;
    }
    // P (mean prob) and f (top-2 counts) partial sums for experts [16W, 16W+16)
    #pragma unroll
    for (int c = 0; c < 16; ++c) {
        const int e = W * 16 + c;
        float val = v[e] * rZ;
        #pragma unroll
        for (int off = 32; off > 0; off >>= 1) val += __shfl_xor(val, off, 64);
        unsigned long long b1 = __ballot(i1 == e);
        unsigned long long b2 = __ballot(i2 == e);
        if (lane == c) {
            atomicAdd(Pacc + e, val);
            atomicAdd(Facc + e, (float)(__popcll(b1) + __popcll(b2)));
        }
    }
}

// ---------------- kernel 2: main fused router --------------------------------------
__global__ __launch_bounds__(256, 1) void k2_main(const float* __restrict__ x,
                                                  const float* __restrict__ Wr,
                                                  float* __restrict__ ws,
                                                  float* __restrict__ out) {
    __shared__ float xT[BK * SX];     // x tile, transposed [k][t], padded
    __shared__ float wT[BK * SX];     // W tile, transposed [k][e], padded
    __shared__ float lg[64 * SX];     // logits exchange [t][e], padded

    const int tid  = threadIdx.x;
    const int w    = tid >> 6;        // wave 0..3 -> experts [16w,16w+16)
    const int lane = tid & 63;
    const int tg   = lane & 15;       // token group: tokens 4tg..4tg+3
    const int eg   = lane >> 4;       // expert group within wave
    const int tok0 = blockIdx.x * 64;
    const int b    = tok0 >> 12;      // batch index (4096 tokens per b)
    const int e0   = w * 16 + eg * 4; // this lane's 4 contiguous experts

    // staging mapping: thread -> (row, quad)
    const int srow = tid >> 2;        // 0..63 (token row for x, expert row for W)
    const int skq  = tid & 3;
    const float* xg = x  + (size_t)(tok0 + srow) * DIM  + skq * 4;
    const float* wg = Wr + (size_t)srow        * WROW + skq * 4;

    // accumulators init = task logits (incl. expert_bias), same for all 4 tokens
    const float4 tl4 = *(const float4*)(ws + b * 64 + e0);
    float acc[4][4];
    #pragma unroll
    for (int i = 0; i < 4; ++i) {
        acc[i][0] = tl4.x; acc[i][1] = tl4.y; acc[i][2] = tl4.z; acc[i][3] = tl4.w;
    }

    // prologue: prefetch tile 0 into registers
    float4 px[4], pw[4];
    #pragma unroll
    for (int m = 0; m < 4; ++m) {
        px[m] = *(const float4*)(xg + m * 16);
        pw[m] = *(const float4*)(wg + m * 16);
    }

    for (int tile = 0; tile < NTILE; ++tile) {
        __syncthreads();              // previous tile's compute done
        #pragma unroll
        for (int m = 0; m < 4; ++m) {
            const int kk = skq * 4 + m * 16;
            xT[(kk + 0) * SX + srow] = px[m].x; xT[(kk + 1) * SX + srow] = px[m].y;
            xT[(kk + 2) * SX + srow] = px[m].z; xT[(kk + 3) * SX + srow] = px[m].w;
            wT[(kk + 0) * SX + srow] = pw[m].x; wT[(kk + 1) * SX + srow] = pw[m].y;
            wT[(kk + 2) * SX + srow] = pw[m].z; wT[(kk + 3) * SX + srow] = pw[m].w;
        }
        __syncthreads();              // tile visible to all waves
        if (tile + 1 < NTILE) {       // prefetch next tile (latency hides under compute)
            const float* xn = xg + (tile + 1) * BK;
            const float* wn = wg + (tile + 1) * BK;
            #pragma unroll
            for (int m = 0; m < 4; ++m) {
                px[m] = *(const float4*)(xn + m * 16);
                pw[m] = *(const float4*)(wn + m * 16);
            }
        }
        #pragma unroll 8
        for (int k = 0; k < BK; ++k) {
            const float4 xv = *(const float4*)&xT[k * SX + tg * 4];   // 4 tokens @ k
            const float4 wv = *(const float4*)&wT[k * SX + e0];       // 4 experts @ k
            acc[0][0] += xv.x * wv.x; acc[0][1] += xv.x * wv.y;
            acc[0][2] += xv.x * wv.z; acc[0][3] += xv.x * wv.w;
            acc[1][0] += xv.y * wv.x; acc[1][1] += xv.y * wv.y;
            acc[1][2] += xv.y * wv.z; acc[1][3] += xv.y * wv.w;
            acc[2][0] += xv.z * wv.x; acc[2][1] += xv.z * wv.y;
            acc[2][2] += xv.z * wv.z; acc[2][3] += xv.z * wv.w;
            acc[3][0] += xv.w * wv.x; acc[3][1] += xv.w * wv.y;
            acc[3][2] += xv.w * wv.z; acc[3][3] += xv.w * wv.w;
        }
    }

    // exchange logits: lane (tg,eg) owns tokens 4tg..4tg+3 x experts e0..e0+3
    #pragma unroll
    for (int ti = 0; ti < 4; ++ti) {
        float4 v4;
        v4.x = acc[ti][0]; v4.y = acc[ti][1]; v4.z = acc[ti][2]; v4.w = acc[ti][3];
        *(float4*)&lg[(tg * 4 + ti) * SX + e0] = v4;
    }
    __syncthreads();

    // per-lane softmax over full row (lane = token); all waves redundant (cheap)
    float v[64];
    #pragma unroll
    for (int c = 0; c < 16; ++c) {
        const float4 r4 = *(const float4*)&lg[lane * SX + c * 4];
        v[4 * c + 0] = r4.x; v[4 * c + 1] = r4.y; v[4 * c + 2] = r4.z; v[4 * c + 3] = r4.w;
    }
    // top-2 scan (strict > keeps lowest index on ties, matches lax.top_k)
    float m1 = v[0], m2 = -3.4e38f;
    int i1 = 0, i2 = 0;
    #pragma unroll
    for (int e = 1; e < 64; ++e) {
        const float val = v[e];
        const bool g1 = val > m1, g2 = val > m2;
        m2 = g1 ? m1 : (g2 ? val : m2);
        i2 = g1 ? i1 : (g2 ? e : i2);
        m1 = g1 ? val : m1;
        i1 = g1 ? e : i1;
    }
    float z0 = 0.f, z1 = 0.f, z2 = 0.f, z3 = 0.f;
    #pragma unroll
    for (int c = 0; c < 16; ++c) {
        v[4 * c + 0] = __expf(v[4 * c + 0] - m1); z0 += v[4 * c + 0];
        v[4 * c + 1] = __expf(v[4 * c + 1] - m1); z1 += v[4 * c + 1];
        v[4 * c + 2] = __expf(v[4 * c + 2] - m1); z2 += v[4 * c + 2];
        v[4 * c + 3] = __expf(v[4 * c + 3] - m1); z3 += v[4 * c + 3];
    }
    const float Z  = (z0 + z1) + (z2 + z3);
    const float rZ = 1.0f / Z;
    const float p2 = __expf(m2 - m1);          // p1 = 1
    const float q1 = rZ, q2 = p2 * rZ;
    const float dn = 1.0f / (q1 + q2 + 1e-8f);
    const int   T  = tok0 + lane;

    if (w == 0) {
        float2 tw; tw.x = q1 * dn; tw.y = q2 * dn;
        *(float2*)(out + (size_t)T * 2) = tw;
        float2 ti2; ti2.x = (float)i1; ti2.y = (float)i2;
        *(float2*)(out + 32768 + (size_t)T * 2) = ti2;
    }

    float* pb   = out + 65536 + (size_t)T * 64;
    float* Pacc = ws + 256;
    float* Facc = ws + 320;
    if      (w == 0) epi_part<0>(v, rZ, i1, i2, pb, Pacc, Facc, lane);
    else if (w == 1) epi_part<1>(v, rZ, i1, i2, pb, Pacc, Facc, lane);
    else if (w == 2) epi_part<2>(v, rZ, i1, i2, pb, Pacc, Facc, lane);
    else             epi_part<3>(v, rZ, i1, i2, pb, Pacc, Facc, lane);
}

// ---------------- kernel 3: aux loss ------------------------------------------------
__global__ void k3_aux(const float* __restrict__ ws, float* __restrict__ out) {
    const int lane = threadIdx.x;  // 64 threads
    float val = ws[256 + lane] * ws[320 + lane];   // Pacc[e] * Facc[e]
    #pragma unroll
    for (int off = 32; off > 0; off >>= 1) val += __shfl_xor(val, off, 64);
    if (lane == 0)
        out[1114112] = 64.0f * val / (16384.0f * 2.0f * 16384.0f);
}

extern "C" void kernel_launch(void* const* d_in, const int* in_sizes, int n_in,
                              void* d_out, int out_size, void* d_ws, size_t ws_size,
                              hipStream_t stream) {
    (void)in_sizes; (void)n_in; (void)out_size; (void)ws_size;
    const float* x  = (const float*)d_in[0];
    const float* z  = (const float*)d_in[1];
    const float* Wr = (const float*)d_in[2];
    const float* Wp = (const float*)d_in[3];
    const float* bp = (const float*)d_in[4];
    const float* eb = (const float*)d_in[5];
    float* out = (float*)d_out;
    float* ws  = (float*)d_ws;

    hipLaunchKernelGGL(k1_task, dim3(1),   dim3(256), 0, stream, z, Wp, bp, Wr, eb, ws);
    hipLaunchKernelGGL(k2_main, dim3(256), dim3(256), 0, stream, x, Wr, ws, out);
    hipLaunchKernelGGL(k3_aux,  dim3(1),   dim3(64),  0, stream, ws, out);
}

// Round 2
// 146.998 us; speedup vs baseline: 1.2455x; 1.2455x over previous
//
#include <hip/hip_runtime.h>
#include <math.h>

// TaskAdaptiveRouter: logits = x @ Wr[:, :2048]^T + task_logits; softmax; top2; aux.
// B=4, L=4096 -> 16384 tokens; D=2048; DT=16; E=64; TOP_K=2; TEMP=1.
//
// d_out (f32 flat): [0,32768) topw ; [32768,65536) topi(as float) ;
//                   [65536,1114112) probs ; [1114112] aux.
// d_ws  (f32): [0,256) task logits tl[4][64] ; [256,320) Pacc ; [320,384) Facc.
//
// Plan: k1 tiny task-proj; k2 grid 512 = 256 token-groups(64) x 2 expert-halves(32),
// block=256thr=4 waves, waves split K (512 each), per-lane 8tok x 4exp, LDS reduce,
// plain-store raw logits into the probs region; k3 softmax/top2 in place; k4 aux.

#define DDIM 2048
#define WROW 2064

// ---------------- kernel 1: task projection + task logits + zero accumulators ----
__global__ void k1_task(const float* __restrict__ z, const float* __restrict__ Wp,
                        const float* __restrict__ bp, const float* __restrict__ Wr,
                        const float* __restrict__ eb, float* __restrict__ wsb) {
    __shared__ float tp[4][16];
    const int t = threadIdx.x;
    if (t < 64) {
        const int b = t >> 4, r = t & 15;
        float s = bp[r];
        #pragma unroll
        for (int i = 0; i < 16; ++i) s += z[b * 16 + i] * Wp[r * 16 + i];
        tp[b][r] = 0.5f * s * (1.0f + erff(s * 0.70710678118654752440f));
    }
    if (t < 128) wsb[256 + t] = 0.0f;   // zero Pacc[64] + Facc[64]
    __syncthreads();
    {
        const int b = t >> 6, e = t & 63;
        const float* wr = Wr + (size_t)e * WROW + DDIM;
        float s = eb[e];
        #pragma unroll
        for (int i = 0; i < 16; ++i) s += tp[b][i] * wr[i];
        wsb[b * 64 + e] = s;
    }
}

// ---------------- kernel 2: raw logits -------------------------------------------
// LDS map (words): xT[w][kk 0..31][stride 68]  at  w*2176        (8704 words)
//                  wT[w][kk 0..31][stride 36]  at  8704 + w*1152 (4608 words)
//                  red[w][tok 0..63][stride 36] at w*2304        (reused, 9216)
__global__ __launch_bounds__(256, 2) void k2_logits(const float* __restrict__ x,
                                                    const float* __restrict__ Wr,
                                                    const float* __restrict__ tl,
                                                    float* __restrict__ out) {
    __shared__ __align__(16) float sm[13312];
    const int tid  = threadIdx.x;
    const int w    = tid >> 6, lane = tid & 63;
    const int tg   = lane & 7, eg = lane >> 3;     // 8 tok-groups x 8 exp-groups
    const int bid  = blockIdx.x;
    const int tok0  = (bid >> 1) * 64;
    const int ebase = (bid & 1) * 32;

    // staging roles
    const int sxt = tid & 63, sxq = tid >> 6;      // x: token row, K-chunk
    const int swe = tid & 31, swc = tid >> 5;      // W: expert row, (chunk*2+half)
    const float* xg = x  + (size_t)(tok0 + sxt) * DDIM + sxq * 512;
    const float* wg = Wr + (size_t)(ebase + swe) * WROW + (swc >> 1) * 512 + (swc & 1) * 16;

    float4 px[8], pw[4];
    #pragma unroll
    for (int m = 0; m < 8; ++m) px[m] = *(const float4*)(xg + m * 4);
    #pragma unroll
    for (int m = 0; m < 4; ++m) pw[m] = *(const float4*)(wg + m * 4);

    float acc[8][4];
    #pragma unroll
    for (int t = 0; t < 8; ++t)
        #pragma unroll
        for (int e = 0; e < 4; ++e) acc[t][e] = 0.0f;

    float*       xs  = sm + sxq * 2176;                                  // store x
    float*       wst = sm + 8704 + (swc >> 1) * 1152 + (swc & 1) * 576 + swe; // store W
    const float* xr  = sm + w * 2176 + 8 * tg;                           // read x
    const float* wr  = sm + 8704 + w * 1152 + 4 * eg;                    // read W

    for (int tile = 0; tile < 16; ++tile) {
        __syncthreads();
        #pragma unroll
        for (int m = 0; m < 8; ++m) {
            xs[(4 * m + 0) * 68 + sxt] = px[m].x;
            xs[(4 * m + 1) * 68 + sxt] = px[m].y;
            xs[(4 * m + 2) * 68 + sxt] = px[m].z;
            xs[(4 * m + 3) * 68 + sxt] = px[m].w;
        }
        #pragma unroll
        for (int m = 0; m < 4; ++m) {
            wst[(4 * m + 0) * 36] = pw[m].x;
            wst[(4 * m + 1) * 36] = pw[m].y;
            wst[(4 * m + 2) * 36] = pw[m].z;
            wst[(4 * m + 3) * 36] = pw[m].w;
        }
        __syncthreads();
        if (tile < 15) {                    // prefetch next tile (hidden by compute)
            const float* xn = xg + (tile + 1) * 32;
            const float* wn = wg + (tile + 1) * 32;
            #pragma unroll
            for (int m = 0; m < 8; ++m) px[m] = *(const float4*)(xn + m * 4);
            #pragma unroll
            for (int m = 0; m < 4; ++m) pw[m] = *(const float4*)(wn + m * 4);
        }
        #pragma unroll 4
        for (int kk = 0; kk < 32; ++kk) {
            const float4 xa = *(const float4*)(xr + kk * 68);
            const float4 xb = *(const float4*)(xr + kk * 68 + 4);
            const float4 wv = *(const float4*)(wr + kk * 36);
            const float xv[8] = {xa.x, xa.y, xa.z, xa.w, xb.x, xb.y, xb.z, xb.w};
            const float wvv[4] = {wv.x, wv.y, wv.z, wv.w};
            #pragma unroll
            for (int t = 0; t < 8; ++t)
                #pragma unroll
                for (int e = 0; e < 4; ++e) acc[t][e] += xv[t] * wvv[e];
        }
    }

    // cross-wave K reduction through LDS (once per block)
    __syncthreads();
    #pragma unroll
    for (int t = 0; t < 8; ++t) {
        float4 v4;
        v4.x = acc[t][0]; v4.y = acc[t][1]; v4.z = acc[t][2]; v4.w = acc[t][3];
        *(float4*)(sm + w * 2304 + (8 * tg + t) * 36 + 4 * eg) = v4;
    }
    __syncthreads();

    const int ot = tid >> 2, oq = tid & 3;        // token, 8-expert quad
    float s0x = 0, s0y = 0, s0z = 0, s0w = 0, s1x = 0, s1y = 0, s1z = 0, s1w = 0;
    #pragma unroll
    for (int w2 = 0; w2 < 4; ++w2) {
        const float* r = sm + w2 * 2304 + ot * 36 + 8 * oq;
        const float4 a = *(const float4*)r;
        const float4 b4 = *(const float4*)(r + 4);
        s0x += a.x; s0y += a.y; s0z += a.z; s0w += a.w;
        s1x += b4.x; s1y += b4.y; s1z += b4.z; s1w += b4.w;
    }
    const int bb = tok0 >> 12;                    // batch (64 | 4096, uniform per block)
    const float4 t0 = *(const float4*)(tl + bb * 64 + ebase + 8 * oq);
    const float4 t1 = *(const float4*)(tl + bb * 64 + ebase + 8 * oq + 4);
    float4 o0, o1;
    o0.x = s0x + t0.x; o0.y = s0y + t0.y; o0.z = s0z + t0.z; o0.w = s0w + t0.w;
    o1.x = s1x + t1.x; o1.y = s1y + t1.y; o1.z = s1z + t1.z; o1.w = s1w + t1.w;
    float* o = out + 65536 + (size_t)(tok0 + ot) * 64 + ebase + 8 * oq;
    *(float4*)o = o0;
    *(float4*)(o + 4) = o1;
}

// ---------------- kernel 3: softmax + top2 + probs + P/f -------------------------
__global__ __launch_bounds__(256, 2) void k3_soft(float* __restrict__ out,
                                                  float* __restrict__ wsb) {
    const int tid = threadIdx.x, w = tid >> 6, lane = tid & 63;
    const int base = blockIdx.x * 32 + w * 8;
    float pacc = 0.0f, facc = 0.0f;
    for (int i = 0; i < 8; ++i) {
        const int T = base + i;
        float* row = out + 65536 + (size_t)T * 64;
        const float v = row[lane];
        // argmax (lowest index on ties, matches lax.top_k)
        float m1 = v; int i1 = lane;
        #pragma unroll
        for (int off = 32; off; off >>= 1) {
            const float ov = __shfl_xor(m1, off, 64);
            const int   oi = __shfl_xor(i1, off, 64);
            if (ov > m1 || (ov == m1 && oi < i1)) { m1 = ov; i1 = oi; }
        }
        const float vx = (lane == i1) ? -3.4e38f : v;
        float m2 = vx; int i2 = lane;
        #pragma unroll
        for (int off = 32; off; off >>= 1) {
            const float ov = __shfl_xor(m2, off, 64);
            const int   oi = __shfl_xor(i2, off, 64);
            if (ov > m2 || (ov == m2 && oi < i2)) { m2 = ov; i2 = oi; }
        }
        const float p = __expf(v - m1);
        float s = p;
        #pragma unroll
        for (int off = 32; off; off >>= 1) s += __shfl_xor(s, off, 64);
        const float rZ = 1.0f / s;
        const float pn = p * rZ;
        row[lane] = pn;                       // probs, coalesced 256B
        pacc += pn;
        facc += (lane == i1 ? 1.0f : 0.0f) + (lane == i2 ? 1.0f : 0.0f);
        if (lane == 0) {
            const float q1 = rZ, q2 = __expf(m2 - m1) * rZ;
            const float dn = 1.0f / (q1 + q2 + 1e-8f);
            float2 tw; tw.x = q1 * dn; tw.y = q2 * dn;
            *(float2*)(out + (size_t)T * 2) = tw;
            float2 ti; ti.x = (float)i1; ti.y = (float)i2;
            *(float2*)(out + 32768 + (size_t)T * 2) = ti;
        }
    }
    atomicAdd(wsb + 256 + lane, pacc);        // lane == expert
    atomicAdd(wsb + 320 + lane, facc);
}

// ---------------- kernel 4: aux loss ----------------------------------------------
__global__ void k4_aux(const float* __restrict__ wsb, float* __restrict__ out) {
    const int lane = threadIdx.x;  // 64 threads
    float val = wsb[256 + lane] * wsb[320 + lane];
    #pragma unroll
    for (int off = 32; off; off >>= 1) val += __shfl_xor(val, off, 64);
    if (lane == 0)
        out[1114112] = 64.0f * val / (16384.0f * 2.0f * 16384.0f);
}

extern "C" void kernel_launch(void* const* d_in, const int* in_sizes, int n_in,
                              void* d_out, int out_size, void* d_ws, size_t ws_size,
                              hipStream_t stream) {
    (void)in_sizes; (void)n_in; (void)out_size; (void)ws_size;
    const float* x  = (const float*)d_in[0];
    const float* z  = (const float*)d_in[1];
    const float* Wr = (const float*)d_in[2];
    const float* Wp = (const float*)d_in[3];
    const float* bp = (const float*)d_in[4];
    const float* eb = (const float*)d_in[5];
    float* out = (float*)d_out;
    float* wsb = (float*)d_ws;

    hipLaunchKernelGGL(k1_task,   dim3(1),   dim3(256), 0, stream, z, Wp, bp, Wr, eb, wsb);
    hipLaunchKernelGGL(k2_logits, dim3(512), dim3(256), 0, stream, x, Wr, wsb, out);
    hipLaunchKernelGGL(k3_soft,   dim3(512), dim3(256), 0, stream, out, wsb);
    hipLaunchKernelGGL(k4_aux,    dim3(1),   dim3(64),  0, stream, wsb, out);
}